// Round 1
// baseline (689.703 us; speedup 1.0000x reference)
//
#include <hip/hip_runtime.h>

typedef _Float16 half8 __attribute__((ext_vector_type(8)));
typedef float floatx16 __attribute__((ext_vector_type(16)));

#define B_  16
#define S_  2048
#define D_  256
#define P_RS 40
#define LOG2E 1.4426950408889634f

#define DPP_ROR(x, n) __int_as_float(__builtin_amdgcn_update_dpp( \
    0, __float_as_int(x), 0x120 + (n), 0xf, 0xf, false))

__device__ __forceinline__ float rmax32(float x) {
    x = fmaxf(x, DPP_ROR(x, 1));
    x = fmaxf(x, DPP_ROR(x, 2));
    x = fmaxf(x, DPP_ROR(x, 4));
    x = fmaxf(x, DPP_ROR(x, 8));
    x = fmaxf(x, __shfl_xor(x, 16, 64));
    return x;
}
__device__ __forceinline__ float rsum32(float x) {
    x += DPP_ROR(x, 1);
    x += DPP_ROR(x, 2);
    x += DPP_ROR(x, 4);
    x += DPP_ROR(x, 8);
    x += __shfl_xor(x, 16, 64);
    return x;
}

// async 16B/lane global -> LDS DMA; lds base wave-uniform, HW adds lane*16
__device__ __forceinline__ void dma16(const _Float16* g, _Float16* l) {
    __builtin_amdgcn_global_load_lds(
        (const __attribute__((address_space(1))) void*)g,
        (__attribute__((address_space(3))) void*)l, 16, 0, 0);
}

// out[c][r] (f16) = in[r][c] (f32). If swz: 16B-chunk c' = (c&~7)|((c&7)^((row>>1)&7))
// so the main kernel's LDS-resident K rows have bank-even fragment reads.
__global__ __launch_bounds__(256)
void tr_swz(const float* __restrict__ in, _Float16* __restrict__ out,
            int Rin, int Cin, int swz)
{
    __shared__ _Float16 tl[64 * 72];
    const int t  = threadIdx.x;
    const int c0 = blockIdx.x * 64, r0 = blockIdx.y * 64;
    const float* ib = in  + (size_t)blockIdx.z * Rin * Cin;
    _Float16*    ob = out + (size_t)blockIdx.z * Rin * Cin;

    const int rr = t >> 4, cc = (t & 15) * 4;
    #pragma unroll
    for (int p = 0; p < 4; ++p) {
        const float4 x = *(const float4*)(ib + (size_t)(r0 + rr + 16*p) * Cin + c0 + cc);
        tl[(cc+0)*72 + rr + 16*p] = (_Float16)x.x;
        tl[(cc+1)*72 + rr + 16*p] = (_Float16)x.y;
        tl[(cc+2)*72 + rr + 16*p] = (_Float16)x.z;
        tl[(cc+3)*72 + rr + 16*p] = (_Float16)x.w;
    }
    __syncthreads();
    #pragma unroll
    for (int u = 0; u < 2; ++u) {
        const int idx  = t + 256*u;
        const int jloc = idx >> 3, lc = idx & 7;
        const half8 h = *(const half8*)(tl + jloc*72 + 8*lc);
        const int jg  = c0 + jloc;
        const int lco = swz ? (lc ^ ((jg >> 1) & 7)) : lc;
        *(half8*)(ob + (size_t)jg * Rin + r0 + 8*lco) = h;
    }
}

// v5: 4 waves/block = 2 query strips x 2 KV halves. Doubles wave count
// (1024 -> 2048 = 2 waves/SIMD) to hide the per-tile serial-chain latency
// that capped v4 at Occupancy 11% / MfmaUtil 12%. Halves merge in-block
// via LDS (online-softmax merge), reusing kb post-loop as scratch.
__global__ __launch_bounds__(256, 2)
void attn_v5(const float* __restrict__ q, const _Float16* __restrict__ kts,
             const _Float16* __restrict__ vt, const int* __restrict__ mask,
             float* __restrict__ out)
{
    __shared__ _Float16 kb[2][2][32 * D_];   // [half][dbuf] K tiles (swizzled rows)
    __shared__ _Float16 pbuf[4][32 * P_RS];  // per-wave P strips

    const int tid   = threadIdx.x;
    const int w     = tid >> 6;
    const int strip = w & 1;                 // which 32-row Q strip
    const int half  = w >> 1;                // which KV half (0: tiles 0..31, 1: 32..63)
    const int lane  = tid & 63;
    const int jl    = lane & 31;
    const int h     = lane >> 5;
    const int pj    = (jl >> 1) & 7;

    // XCD swizzle: each XCD owns 2 batches x 32 row-groups
    const int bx   = blockIdx.x;
    const int rest = bx >> 3;
    const int b    = 2 * (bx & 7) + (rest >> 5);
    const int qg   = rest & 31;
    const int i0   = qg * 64 + 32 * strip;   // this wave's 32-row strip

    const float*    qb  = q    + (size_t)b * S_ * D_;
    const _Float16* ktb = kts  + (size_t)b * S_ * D_;   // [S][D] swizzled
    const _Float16* vtb = vt   + (size_t)b * S_ * D_;   // [D][S]
    const int*      mb  = mask + (size_t)b * S_;
    float*          ob  = out  + (size_t)b * D_ * S_;

    // Q A-frags: A[m=i0+jl][k=16s+8h+0..7]
    half8 qf[16];
    {
        const float* qrow = qb + (size_t)(i0 + jl) * D_;
        #pragma unroll
        for (int s = 0; s < 16; ++s) {
            const float4 a = *(const float4*)(qrow + 16*s + 8*h);
            const float4 c = *(const float4*)(qrow + 16*s + 8*h + 4);
            half8 v;
            v[0]=(_Float16)a.x; v[1]=(_Float16)a.y; v[2]=(_Float16)a.z; v[3]=(_Float16)a.w;
            v[4]=(_Float16)c.x; v[5]=(_Float16)c.y; v[6]=(_Float16)c.z; v[7]=(_Float16)c.w;
            qf[s] = v;
        }
    }

    floatx16 o[8];
    #pragma unroll
    for (int nt = 0; nt < 8; ++nt) o[nt] = (floatx16){};
    float M[16], pc[16], lsum[16];
    #pragma unroll
    for (int r = 0; r < 16; ++r) { M[r] = -3.0e38f; pc[r] = 0.0f; lsum[r] = 0.0f; }

    _Float16* pw = pbuf[w];
    const int tbase = half * 32;

    // preload this half's K tile 0 (wave stages rows 16*strip..+15; 2 rows/DMA)
    #pragma unroll
    for (int m = 0; m < 8; ++m)
        dma16(ktb + (size_t)(32*tbase + 16*strip + 2*m) * D_ + lane*8,
              kb[half][0] + (16*strip + 2*m) * D_);
    __syncthreads();

    for (int tt = 0; tt < 32; ++tt) {
        const int t  = tbase + tt;
        const int j0 = 32 * t;
        const int jn = ((t + 1) & 63) * 32;      // wraps harmlessly on last iter
        const _Float16* kcur = kb[half][tt & 1];
        _Float16*       knxt = kb[half][(tt + 1) & 1];

        // prefetch next K tile via async DMA (landed by iter-end barrier)
        #pragma unroll
        for (int m = 0; m < 8; ++m)
            dma16(ktb + (size_t)(jn + 16*strip + 2*m) * D_ + lane*8,
                  knxt + (16*strip + 2*m) * D_);

        // hoist V frags (B[n=32nt+jl][k=16ks+8h+..]) + mask; used ~800 cyc later
        half8 vf0[8], vf1[8];
        #pragma unroll
        for (int nt = 0; nt < 8; ++nt) {
            const _Float16* vr = vtb + (size_t)(32*nt + jl) * S_ + j0 + 8*h;
            vf0[nt] = *(const half8*)(vr);
            vf1[nt] = *(const half8*)(vr + 16);
        }
        const float mo = mb[j0 + jl] ? 0.0f : -1.0e9f;

        // S = Q K^T from LDS (swizzled chunks), two accumulation chains
        floatx16 sa = (floatx16){}, sb = (floatx16){};
        #pragma unroll
        for (int s = 0; s < 16; s += 2) {
            const half8 k0 = *(const half8*)(kcur + jl*D_ + 8*((2*s     + h) ^ pj));
            const half8 k1 = *(const half8*)(kcur + jl*D_ + 8*((2*s + 2 + h) ^ pj));
            sa = __builtin_amdgcn_mfma_f32_32x32x16_f16(qf[s],   k0, sa, 0,0,0);
            sb = __builtin_amdgcn_mfma_f32_32x32x16_f16(qf[s+1], k1, sb, 0,0,0);
        }
        float sv[16];
        #pragma unroll
        for (int r = 0; r < 16; ++r) sv[r] = sa[r] + sb[r] + mo;

        // lazy online max: only rescale when some row exceeds reference M by >8
        float mx = sv[0] - M[0];
        #pragma unroll
        for (int r = 1; r < 16; ++r) mx = fmaxf(mx, sv[r] - M[r]);
        if (__any(mx > 8.0f)) {
            #pragma unroll
            for (int r = 0; r < 16; ++r) {
                const float tm = rmax32(sv[r]);
                const float Mn = fmaxf(M[r], tm);
                const float al = __builtin_amdgcn_exp2f((M[r] - Mn) * LOG2E);
                M[r] = Mn; pc[r] = -Mn * LOG2E;
                lsum[r] *= al;
                #pragma unroll
                for (int nt = 0; nt < 8; ++nt) o[nt][r] *= al;
            }
        }

        // p = e^(sv-M) (<= e^8, f16-safe); deferred per-lane row sums
        #pragma unroll
        for (int r = 0; r < 16; ++r) {
            const float p = __builtin_amdgcn_exp2f(fmaf(sv[r], LOG2E, pc[r]));
            lsum[r] += p;
            pw[((r&3) + 8*(r>>2) + 4*h) * P_RS + jl] = (_Float16)p;
        }
        asm volatile("s_waitcnt lgkmcnt(0)" ::: "memory");
        const half8 pa0 = *(const half8*)(pw + jl*P_RS + 8*h);
        const half8 pa1 = *(const half8*)(pw + jl*P_RS + 16 + 8*h);

        #pragma unroll
        for (int nt = 0; nt < 8; ++nt) {
            o[nt] = __builtin_amdgcn_mfma_f32_32x32x16_f16(pa0, vf0[nt], o[nt], 0,0,0);
            o[nt] = __builtin_amdgcn_mfma_f32_32x32x16_f16(pa1, vf1[nt], o[nt], 0,0,0);
        }

        // drains K(t+1) DMA + protects kcur from next iter's DMA overwrite
        __syncthreads();
    }

    // ---- in-block merge of the two KV halves (online-softmax merge) ----
    // kb (64 KB) is dead now: strip s scratch = 32 KB at ob32 + s*8192 floats.
    // pbuf overlay holds per-row {M, reduced lsum} of half 1.
    float* ob32 = (float*)kb;
    float* stat = (float*)pbuf;
    float* ms   = ob32 + strip * 8192;

    if (half == 1) {
        #pragma unroll
        for (int nt = 0; nt < 8; ++nt)
            #pragma unroll
            for (int r = 0; r < 16; ++r)
                ms[(nt*16 + r)*64 + lane] = o[nt][r];   // [elem][lane]: conflict-free
        #pragma unroll
        for (int r = 0; r < 16; ++r) {
            const float lr = rsum32(lsum[r]);
            if (jl == 0) {
                const int row = (r&3) + 8*(r>>2) + 4*h;
                stat[strip*64 + row*2]     = M[r];
                stat[strip*64 + row*2 + 1] = lr;
            }
        }
    }
    __syncthreads();
    if (half == 0) {
        float sA[16], sB[16], osc[16];
        #pragma unroll
        for (int r = 0; r < 16; ++r) {
            const int row  = (r&3) + 8*(r>>2) + 4*h;
            const float MB = stat[strip*64 + row*2];
            const float lB = stat[strip*64 + row*2 + 1];
            const float lA = rsum32(lsum[r]);
            const float Mm = fmaxf(M[r], MB);
            sA[r] = __builtin_amdgcn_exp2f((M[r] - Mm) * LOG2E);
            sB[r] = __builtin_amdgcn_exp2f((MB   - Mm) * LOG2E);
            osc[r] = 1.0f / (16.0f * (sA[r]*lA + sB[r]*lB));
        }
        #pragma unroll
        for (int nt = 0; nt < 8; ++nt) {
            float* od = ob + (size_t)(32*nt + jl) * S_ + i0;
            #pragma unroll
            for (int r = 0; r < 16; ++r) {
                const float ov = sA[r]*o[nt][r] + sB[r]*ms[(nt*16 + r)*64 + lane];
                od[(r&3) + 8*(r>>2) + 4*h] = ov * osc[r];
            }
        }
    }
}

extern "C" void kernel_launch(void* const* d_in, const int* in_sizes, int n_in,
                              void* d_out, int out_size, void* d_ws, size_t ws_size,
                              hipStream_t stream)
{
    const float* q    = (const float*)d_in[0];
    const float* k    = (const float*)d_in[1];   // [B][D][S]
    const float* v    = (const float*)d_in[2];   // [B][S][D]
    const int*   mask = (const int*)d_in[3];
    float*       out  = (float*)d_out;

    _Float16* kt = (_Float16*)d_ws;               // [B][S][D] swizzled
    _Float16* vtp = kt + (size_t)B_ * S_ * D_;    // [B][D][S]

    // K: [256][2048] -> swizzled [2048][256]
    tr_swz<<<dim3(S_/64, D_/64, B_), dim3(256), 0, stream>>>(k, kt, D_, S_, 1);
    // V: [2048][256] -> [256][2048]
    tr_swz<<<dim3(D_/64, S_/64, B_), dim3(256), 0, stream>>>(v, vtp, S_, D_, 0);

    attn_v5<<<dim3(B_ * (S_/64)), dim3(256), 0, stream>>>(q, kt, vtp, mask, out);
}

// Round 2
// 340.557 us; speedup vs baseline: 2.0252x; 2.0252x over previous
//
#include <hip/hip_runtime.h>

typedef _Float16 half8 __attribute__((ext_vector_type(8)));
typedef float floatx16 __attribute__((ext_vector_type(16)));

#define B_  16
#define S_  2048
#define D_  256
#define P_RS 40
#define LOG2E 1.4426950408889634f

#define DPP_ROR(x, n) __int_as_float(__builtin_amdgcn_update_dpp( \
    0, __float_as_int(x), 0x120 + (n), 0xf, 0xf, false))

__device__ __forceinline__ float rmax32(float x) {
    x = fmaxf(x, DPP_ROR(x, 1));
    x = fmaxf(x, DPP_ROR(x, 2));
    x = fmaxf(x, DPP_ROR(x, 4));
    x = fmaxf(x, DPP_ROR(x, 8));
    x = fmaxf(x, __shfl_xor(x, 16, 64));
    return x;
}
__device__ __forceinline__ float rsum32(float x) {
    x += DPP_ROR(x, 1);
    x += DPP_ROR(x, 2);
    x += DPP_ROR(x, 4);
    x += DPP_ROR(x, 8);
    x += __shfl_xor(x, 16, 64);
    return x;
}

// async 16B/lane global -> LDS DMA; lds base wave-uniform, HW adds lane*16
__device__ __forceinline__ void dma16(const _Float16* g, _Float16* l) {
    __builtin_amdgcn_global_load_lds(
        (const __attribute__((address_space(1))) void*)g,
        (__attribute__((address_space(3))) void*)l, 16, 0, 0);
}

// out[c][r] (f16) = in[r][c] (f32). If swz: 16B-chunk c' = (c&~7)|((c&7)^((row>>1)&7))
__global__ __launch_bounds__(256)
void tr_swz(const float* __restrict__ in, _Float16* __restrict__ out,
            int Rin, int Cin, int swz)
{
    __shared__ _Float16 tl[64 * 72];
    const int t  = threadIdx.x;
    const int c0 = blockIdx.x * 64, r0 = blockIdx.y * 64;
    const float* ib = in  + (size_t)blockIdx.z * Rin * Cin;
    _Float16*    ob = out + (size_t)blockIdx.z * Rin * Cin;

    const int rr = t >> 4, cc = (t & 15) * 4;
    #pragma unroll
    for (int p = 0; p < 4; ++p) {
        const float4 x = *(const float4*)(ib + (size_t)(r0 + rr + 16*p) * Cin + c0 + cc);
        tl[(cc+0)*72 + rr + 16*p] = (_Float16)x.x;
        tl[(cc+1)*72 + rr + 16*p] = (_Float16)x.y;
        tl[(cc+2)*72 + rr + 16*p] = (_Float16)x.z;
        tl[(cc+3)*72 + rr + 16*p] = (_Float16)x.w;
    }
    __syncthreads();
    #pragma unroll
    for (int u = 0; u < 2; ++u) {
        const int idx  = t + 256*u;
        const int jloc = idx >> 3, lc = idx & 7;
        const half8 h = *(const half8*)(tl + jloc*72 + 8*lc);
        const int jg  = c0 + jloc;
        const int lco = swz ? (lc ^ ((jg >> 1) & 7)) : lc;
        *(half8*)(ob + (size_t)jg * Rin + r0 + 8*lco) = h;
    }
}

// v6: producer/consumer wave specialization. Waves 0,1 (strips 0,1) run
// QK^T + online softmax and publish P(t)+rescale factors to LDS; waves 2,3
// run PV one tile behind and own the output. Each role's live set fits
// <256 unified regs (v4's monolithic wave needed ~350 -> 1 wave/SIMD;
// v5's cap without cutting state spilled 1.1 GB to scratch). Roles live in
// disjoint wave-uniform branches so the allocator sees max(A,B), not sum.
// Barrier counts per role: 1 + 64 + 1 = 66 on both paths.
__global__ __launch_bounds__(256, 2)
void attn_v6(const float* __restrict__ q, const _Float16* __restrict__ kts,
             const _Float16* __restrict__ vt, const int* __restrict__ mask,
             float* __restrict__ out)
{
    __shared__ _Float16 kb[2][32 * D_];          // K tile dbuf (swizzled rows)
    __shared__ _Float16 pbuf[2][2][32 * P_RS];   // [strip][buf] P strips
    __shared__ float    alb [2][2][32];          // [strip][buf] o-rescale per row
    __shared__ float    oscb[2][32];             // final 1/(16*l) per row
    __shared__ int      flg [2][2];              // rescale happened this tile?

    const int tid   = threadIdx.x;
    const int w     = tid >> 6;
    const int strip = w & 1;                 // which 32-row Q strip
    const int isB   = w >> 1;                // 0 = producer, 1 = consumer
    const int lane  = tid & 63;
    const int jl    = lane & 31;
    const int h     = lane >> 5;
    const int pj    = (jl >> 1) & 7;

    // XCD swizzle: each XCD owns 2 batches x 32 row-groups
    const int bx   = blockIdx.x;
    const int rest = bx >> 3;
    const int b    = 2 * (bx & 7) + (rest >> 5);
    const int qg   = rest & 31;
    const int i0   = qg * 64 + 32 * strip;   // this block-strip's 32 q rows

    const float*    qb  = q    + (size_t)b * S_ * D_;
    const _Float16* ktb = kts  + (size_t)b * S_ * D_;   // [S][D] swizzled
    const _Float16* vtb = vt   + (size_t)b * S_ * D_;   // [D][S]
    const int*      mb  = mask + (size_t)b * S_;
    float*          ob  = out  + (size_t)b * D_ * S_;

    if (!isB) {
        // ================= producer: QK^T + online softmax =================
        half8 qf[16];
        {
            const float* qrow = qb + (size_t)(i0 + jl) * D_;
            #pragma unroll
            for (int s = 0; s < 16; ++s) {
                const float4 a = *(const float4*)(qrow + 16*s + 8*h);
                const float4 c = *(const float4*)(qrow + 16*s + 8*h + 4);
                half8 v;
                v[0]=(_Float16)a.x; v[1]=(_Float16)a.y; v[2]=(_Float16)a.z; v[3]=(_Float16)a.w;
                v[4]=(_Float16)c.x; v[5]=(_Float16)c.y; v[6]=(_Float16)c.z; v[7]=(_Float16)c.w;
                qf[s] = v;
            }
        }
        float M[16], lsum[16];
        #pragma unroll
        for (int r = 0; r < 16; ++r) { M[r] = -3.0e38f; lsum[r] = 0.0f; }

        // stage K tile 0 (strip s stages rows 16s..16s+15; 2 rows per DMA)
        #pragma unroll
        for (int m = 0; m < 8; ++m)
            dma16(ktb + (size_t)(16*strip + 2*m) * D_ + lane*8,
                  kb[0] + (16*strip + 2*m) * D_);
        __syncthreads();                                     // bar 0

        for (int t = 0; t < 64; ++t) {
            const int j0 = 32 * t;
            const int jn = ((t + 1) & 63) * 32;  // wraps harmlessly on last iter
            const _Float16* kcur = kb[t & 1];
            _Float16*       knxt = kb[(t + 1) & 1];

            // prefetch next K tile (lands by this iter's barrier)
            #pragma unroll
            for (int m = 0; m < 8; ++m)
                dma16(ktb + (size_t)(jn + 16*strip + 2*m) * D_ + lane*8,
                      knxt + (16*strip + 2*m) * D_);

            const float mo = mb[j0 + jl] ? 0.0f : -1.0e9f;

            floatx16 sa = (floatx16){}, sb = (floatx16){};
            #pragma unroll
            for (int s = 0; s < 16; s += 2) {
                const half8 k0 = *(const half8*)(kcur + jl*D_ + 8*((2*s     + h) ^ pj));
                const half8 k1 = *(const half8*)(kcur + jl*D_ + 8*((2*s + 2 + h) ^ pj));
                sa = __builtin_amdgcn_mfma_f32_32x32x16_f16(qf[s],   k0, sa, 0,0,0);
                sb = __builtin_amdgcn_mfma_f32_32x32x16_f16(qf[s+1], k1, sb, 0,0,0);
            }
            float sv[16];
            #pragma unroll
            for (int r = 0; r < 16; ++r) sv[r] = sa[r] + sb[r] + mo;

            // lazy online max: rescale only when some row exceeds M by >8
            float mx = sv[0] - M[0];
            #pragma unroll
            for (int r = 1; r < 16; ++r) mx = fmaxf(mx, sv[r] - M[r]);
            const bool resc = __any(mx > 8.0f);
            if (resc) {
                #pragma unroll
                for (int r = 0; r < 16; ++r) {
                    const float tm = rmax32(sv[r]);
                    const float Mn = fmaxf(M[r], tm);
                    const float al = __builtin_amdgcn_exp2f((M[r] - Mn) * LOG2E);
                    M[r] = Mn;
                    lsum[r] *= al;
                    if (jl == 0) alb[strip][t & 1][(r&3) + 8*(r>>2) + 4*h] = al;
                }
            }
            if (lane == 0) flg[strip][t & 1] = resc ? 1 : 0;

            // p = e^(sv-M) (<= e^8, f16-safe); publish P strip
            _Float16* pw = pbuf[strip][t & 1];
            #pragma unroll
            for (int r = 0; r < 16; ++r) {
                const float p = __builtin_amdgcn_exp2f((sv[r] - M[r]) * LOG2E);
                lsum[r] += p;
                pw[((r&3) + 8*(r>>2) + 4*h) * P_RS + jl] = (_Float16)p;
            }
            __syncthreads();                                 // bars 1..64
        }

        // epilogue: final per-row scale 1/(16*l) -> LDS for the consumer
        #pragma unroll
        for (int r = 0; r < 16; ++r) {
            const float osc = 1.0f / (16.0f * rsum32(lsum[r]));
            if (jl == 0) oscb[strip][(r&3) + 8*(r>>2) + 4*h] = osc;
        }
        __syncthreads();                                     // bar 65
    } else {
        // ================= consumer: PV, one tile behind =================
        floatx16 o[8];
        #pragma unroll
        for (int nt = 0; nt < 8; ++nt) o[nt] = (floatx16){};

        auto pv_step = [&](int tt) {
            const int j0  = 32 * tt;
            const int buf = tt & 1;
            // issue V frag loads first (hide L2 latency under the LDS reads)
            half8 vf0[8], vf1[8];
            #pragma unroll
            for (int nt = 0; nt < 8; ++nt) {
                const _Float16* vr = vtb + (size_t)(32*nt + jl) * S_ + j0 + 8*h;
                vf0[nt] = *(const half8*)(vr);
                vf1[nt] = *(const half8*)(vr + 16);
            }
            if (flg[strip][buf]) {
                #pragma unroll
                for (int r = 0; r < 16; ++r) {
                    const float al = alb[strip][buf][(r&3) + 8*(r>>2) + 4*h];
                    #pragma unroll
                    for (int nt = 0; nt < 8; ++nt) o[nt][r] *= al;
                }
            }
            const _Float16* pw = pbuf[strip][buf];
            const half8 pa0 = *(const half8*)(pw + jl*P_RS + 8*h);
            const half8 pa1 = *(const half8*)(pw + jl*P_RS + 16 + 8*h);
            #pragma unroll
            for (int nt = 0; nt < 8; ++nt) {
                o[nt] = __builtin_amdgcn_mfma_f32_32x32x16_f16(pa0, vf0[nt], o[nt], 0,0,0);
                o[nt] = __builtin_amdgcn_mfma_f32_32x32x16_f16(pa1, vf1[nt], o[nt], 0,0,0);
            }
        };

        __syncthreads();                                     // bar 0
        for (int t = 0; t < 64; ++t) {
            if (t > 0) pv_step(t - 1);
            __syncthreads();                                 // bars 1..64
        }
        pv_step(63);
        __syncthreads();                                     // bar 65

        // store out[b][d][i] with the producer's final scales
        float osc[16];
        #pragma unroll
        for (int r = 0; r < 16; ++r) osc[r] = oscb[strip][(r&3) + 8*(r>>2) + 4*h];
        #pragma unroll
        for (int nt = 0; nt < 8; ++nt) {
            float* od = ob + (size_t)(32*nt + jl) * S_ + i0;
            #pragma unroll
            for (int r = 0; r < 16; ++r)
                od[(r&3) + 8*(r>>2) + 4*h] = o[nt][r] * osc[r];
        }
    }
}

extern "C" void kernel_launch(void* const* d_in, const int* in_sizes, int n_in,
                              void* d_out, int out_size, void* d_ws, size_t ws_size,
                              hipStream_t stream)
{
    const float* q    = (const float*)d_in[0];
    const float* k    = (const float*)d_in[1];   // [B][D][S]
    const float* v    = (const float*)d_in[2];   // [B][S][D]
    const int*   mask = (const int*)d_in[3];
    float*       out  = (float*)d_out;

    _Float16* kt = (_Float16*)d_ws;               // [B][S][D] swizzled
    _Float16* vtp = kt + (size_t)B_ * S_ * D_;    // [B][D][S]

    // K: [256][2048] -> swizzled [2048][256]
    tr_swz<<<dim3(S_/64, D_/64, B_), dim3(256), 0, stream>>>(k, kt, D_, S_, 1);
    // V: [2048][256] -> [256][2048]
    tr_swz<<<dim3(D_/64, S_/64, B_), dim3(256), 0, stream>>>(v, vtp, S_, D_, 0);

    attn_v6<<<dim3(B_ * (S_/64)), dim3(256), 0, stream>>>(q, kt, vtp, mask, out);
}

// Round 3
// 305.046 us; speedup vs baseline: 2.2610x; 1.1164x over previous
//
#include <hip/hip_runtime.h>

typedef _Float16 half8 __attribute__((ext_vector_type(8)));
typedef float floatx16 __attribute__((ext_vector_type(16)));

#define B_  16
#define S_  2048
#define D_  256
#define P_RS 40
#define LOG2E 1.4426950408889634f

#define DPP_ROR(x, n) __int_as_float(__builtin_amdgcn_update_dpp( \
    0, __float_as_int(x), 0x120 + (n), 0xf, 0xf, false))

__device__ __forceinline__ float rmax32(float x) {
    x = fmaxf(x, DPP_ROR(x, 1));
    x = fmaxf(x, DPP_ROR(x, 2));
    x = fmaxf(x, DPP_ROR(x, 4));
    x = fmaxf(x, DPP_ROR(x, 8));
    x = fmaxf(x, __shfl_xor(x, 16, 64));
    return x;
}
__device__ __forceinline__ float rsum32(float x) {
    x += DPP_ROR(x, 1);
    x += DPP_ROR(x, 2);
    x += DPP_ROR(x, 4);
    x += DPP_ROR(x, 8);
    x += __shfl_xor(x, 16, 64);
    return x;
}

// async 16B/lane global -> LDS DMA; lds base wave-uniform, HW adds lane*16
__device__ __forceinline__ void dma16(const _Float16* g, _Float16* l) {
    __builtin_amdgcn_global_load_lds(
        (const __attribute__((address_space(1))) void*)g,
        (__attribute__((address_space(3))) void*)l, 16, 0, 0);
}

// out[c][r] (f16) = in[r][c] (f32). If swz: 16B-chunk c' = (c&~7)|((c&7)^((row>>1)&7))
__global__ __launch_bounds__(256)
void tr_swz(const float* __restrict__ in, _Float16* __restrict__ out,
            int Rin, int Cin, int swz)
{
    __shared__ _Float16 tl[64 * 72];
    const int t  = threadIdx.x;
    const int c0 = blockIdx.x * 64, r0 = blockIdx.y * 64;
    const float* ib = in  + (size_t)blockIdx.z * Rin * Cin;
    _Float16*    ob = out + (size_t)blockIdx.z * Rin * Cin;

    const int rr = t >> 4, cc = (t & 15) * 4;
    #pragma unroll
    for (int p = 0; p < 4; ++p) {
        const float4 x = *(const float4*)(ib + (size_t)(r0 + rr + 16*p) * Cin + c0 + cc);
        tl[(cc+0)*72 + rr + 16*p] = (_Float16)x.x;
        tl[(cc+1)*72 + rr + 16*p] = (_Float16)x.y;
        tl[(cc+2)*72 + rr + 16*p] = (_Float16)x.z;
        tl[(cc+3)*72 + rr + 16*p] = (_Float16)x.w;
    }
    __syncthreads();
    #pragma unroll
    for (int u = 0; u < 2; ++u) {
        const int idx  = t + 256*u;
        const int jloc = idx >> 3, lc = idx & 7;
        const half8 h = *(const half8*)(tl + jloc*72 + 8*lc);
        const int jg  = c0 + jloc;
        const int lco = swz ? (lc ^ ((jg >> 1) & 7)) : lc;
        *(half8*)(ob + (size_t)jg * Rin + r0 + 8*lco) = h;
    }
}

// v7: attack the shared L2/L3 bandwidth wall (per-CU tile rate was invariant
// at ~4.3K cyc across v4/v6 despite 2x occupancy => shared-BW-bound, not
// latency). 128 q-rows/block (4 producer + 4 consumer waves, 256 blocks)
// halves K/V traffic per q-row; V tile now staged in LDS by DMA once per
// block (was:每 consumer wave re-read identical V frags from L2/L3).
// V LDS swizzle folded into per-lane DMA *source* address (LDS dest stays
// linear, per m104/m173); read addresses land bank-uniform (8 lanes/quad =
// the wave64-b128 minimum). PV operands swapped (A=V,B=P; identical frag
// layouts) so the epilogue store is lane-consecutive coalesced and
// rescale/scale collapse to one scalar per lane.
__global__ __launch_bounds__(512, 2)
void attn_v7(const float* __restrict__ q, const _Float16* __restrict__ kts,
             const _Float16* __restrict__ vt, const int* __restrict__ mask,
             float* __restrict__ out)
{
    __shared__ _Float16 kb[2][32 * D_];          // 32 KB: K tile dbuf (swizzled rows)
    __shared__ _Float16 vb[3][32 * D_];          // 48 KB: V tile tri-buf [256 d][32 k] swz
    __shared__ _Float16 pbuf[4][2][32 * P_RS];   // 20 KB: [strip][buf] P strips
    __shared__ float    alb [4][2][32];          // o-rescale per q-row
    __shared__ float    oscb[4][32];             // final 1/(16*l) per q-row
    __shared__ int      flg [4][2];

    const int tid   = threadIdx.x;
    const int w     = tid >> 6;
    const int isC   = w >> 2;                // 0 = producer, 1 = consumer
    const int strip = w & 3;                 // which 32-row Q strip
    const int lane  = tid & 63;
    const int jl    = lane & 31;
    const int h     = lane >> 5;
    const int pj    = (jl >> 1) & 7;

    // XCD swizzle: each XCD owns 2 batches x 16 row-groups
    const int bx   = blockIdx.x;
    const int rest = bx >> 3;
    const int b    = 2 * (bx & 7) + (rest >> 4);
    const int qg   = rest & 15;
    const int i0   = qg * 128 + 32 * strip;  // this strip's 32 q rows

    const float*    qb  = q    + (size_t)b * S_ * D_;
    const _Float16* ktb = kts  + (size_t)b * S_ * D_;   // [S][D] swizzled
    const _Float16* vtb = vt   + (size_t)b * S_ * D_;   // [D][S]
    const int*      mb  = mask + (size_t)b * S_;
    float*          ob  = out  + (size_t)b * D_ * S_;

    if (!isC) {
        // ================= producer: QK^T + online softmax =================
        // V-DMA lane constants: storage chunk q' = lane&7 at pair-group
        // g0+(lane>>3); source chunk q = q'^(g&7) -> row/chunk of V^T tile.
        const int qv  = (lane & 7) ^ ((lane >> 3) & 7);
        const int vdr = 2 * (lane >> 3) + (qv >> 2); // d-row within 16-row group
        const int vco = 8 * (qv & 3);                // k-chunk offset (halfs)
        const _Float16* vsrc = vtb + (size_t)(64*strip + vdr) * S_ + vco;

        half8 qf[16];
        {
            const float* qrow = qb + (size_t)(i0 + jl) * D_;
            #pragma unroll
            for (int s = 0; s < 16; ++s) {
                const float4 a = *(const float4*)(qrow + 16*s + 8*h);
                const float4 c = *(const float4*)(qrow + 16*s + 8*h + 4);
                half8 v;
                v[0]=(_Float16)a.x; v[1]=(_Float16)a.y; v[2]=(_Float16)a.z; v[3]=(_Float16)a.w;
                v[4]=(_Float16)c.x; v[5]=(_Float16)c.y; v[6]=(_Float16)c.z; v[7]=(_Float16)c.w;
                qf[s] = v;
            }
        }
        float M[16], lsum[16];
        #pragma unroll
        for (int r = 0; r < 16; ++r) { M[r] = -3.0e38f; lsum[r] = 0.0f; }

        // stage tile 0: K rows 8s..8s+7 (2 rows/instr), V d-rows 64s..64s+63
        #pragma unroll
        for (int m = 0; m < 4; ++m)
            dma16(ktb + (size_t)(8*strip + 2*m) * D_ + lane*8,
                  kb[0] + (8*strip + 2*m) * D_);
        #pragma unroll
        for (int m = 0; m < 4; ++m)
            dma16(vsrc + (size_t)(16*m) * S_, vb[0] + 2048*strip + 512*m);
        __syncthreads();                                     // bar 0

        int wb = 1;                                          // V buf for tile t+1
        for (int t = 0; t < 64; ++t) {
            const int j0 = 32 * t;
            const int jn = ((t + 1) & 63) * 32;  // wraps harmlessly on last iter
            const _Float16* kcur = kb[t & 1];
            _Float16*       knxt = kb[(t + 1) & 1];

            // prefetch K(t+1), V(t+1) (land by this iter's barrier)
            #pragma unroll
            for (int m = 0; m < 4; ++m)
                dma16(ktb + (size_t)(jn + 8*strip + 2*m) * D_ + lane*8,
                      knxt + (8*strip + 2*m) * D_);
            #pragma unroll
            for (int m = 0; m < 4; ++m)
                dma16(vsrc + jn + (size_t)(16*m) * S_, vb[wb] + 2048*strip + 512*m);
            wb = (wb == 2) ? 0 : wb + 1;

            const float mo = mb[j0 + jl] ? 0.0f : -1.0e9f;

            floatx16 sa = (floatx16){}, sb = (floatx16){};
            #pragma unroll
            for (int s = 0; s < 16; s += 2) {
                const half8 k0 = *(const half8*)(kcur + jl*D_ + 8*((2*s     + h) ^ pj));
                const half8 k1 = *(const half8*)(kcur + jl*D_ + 8*((2*s + 2 + h) ^ pj));
                sa = __builtin_amdgcn_mfma_f32_32x32x16_f16(qf[s],   k0, sa, 0,0,0);
                sb = __builtin_amdgcn_mfma_f32_32x32x16_f16(qf[s+1], k1, sb, 0,0,0);
            }
            float sv[16];
            #pragma unroll
            for (int r = 0; r < 16; ++r) sv[r] = sa[r] + sb[r] + mo;

            // lazy online max: rescale only when some row exceeds M by >8
            float mx = sv[0] - M[0];
            #pragma unroll
            for (int r = 1; r < 16; ++r) mx = fmaxf(mx, sv[r] - M[r]);
            const bool resc = __any(mx > 8.0f);
            if (resc) {
                #pragma unroll
                for (int r = 0; r < 16; ++r) {
                    const float tm = rmax32(sv[r]);
                    const float Mn = fmaxf(M[r], tm);
                    const float al = __builtin_amdgcn_exp2f((M[r] - Mn) * LOG2E);
                    M[r] = Mn;
                    lsum[r] *= al;
                    if (jl == 0) alb[strip][t & 1][(r&3) + 8*(r>>2) + 4*h] = al;
                }
            }
            if (lane == 0) flg[strip][t & 1] = resc ? 1 : 0;

            // p = e^(sv-M) (<= e^8, f16-safe); publish P strip
            _Float16* pw = pbuf[strip][t & 1];
            #pragma unroll
            for (int r = 0; r < 16; ++r) {
                const float p = __builtin_amdgcn_exp2f((sv[r] - M[r]) * LOG2E);
                lsum[r] += p;
                pw[((r&3) + 8*(r>>2) + 4*h) * P_RS + jl] = (_Float16)p;
            }
            __syncthreads();                                 // bars 1..64
        }

        // epilogue: final per-row scale 1/(16*l) -> LDS for the consumer
        #pragma unroll
        for (int r = 0; r < 16; ++r) {
            const float osc = 1.0f / (16.0f * rsum32(lsum[r]));
            if (jl == 0) oscb[strip][(r&3) + 8*(r>>2) + 4*h] = osc;
        }
        __syncthreads();                                     // bar 65
    } else {
        // ================= consumer: PV from LDS, one tile behind ==========
        // V read: pair-group g = 16nt+(jl>>1); chunk q = 4*(jl&1)+2ks+h stored
        // at q^(g&7). 8 lanes/bank-quad = wave64-b128 minimum: conflict-free.
        const int gb  = jl >> 1;
        const int swz = gb & 7;
        const int x0  = 4*(jl & 1) + h;
        const int vo0 = gb*64 + ((x0    ) ^ swz)*8;   // ks=0 (k 0..15 half)
        const int vo1 = gb*64 + ((x0 ^ 2) ^ swz)*8;   // ks=1 (k 16..31 half)

        floatx16 o[8];
        #pragma unroll
        for (int nt = 0; nt < 8; ++nt) o[nt] = (floatx16){};

        auto pv_step = [&](int tt, int vbi) {
            const int buf = tt & 1;
            if (flg[strip][buf]) {
                const float al = alb[strip][buf][jl];
                #pragma unroll
                for (int nt = 0; nt < 8; ++nt)
                    #pragma unroll
                    for (int r = 0; r < 16; ++r) o[nt][r] *= al;
            }
            const _Float16* pw  = pbuf[strip][buf];
            const _Float16* vbt = vb[vbi];
            const half8 pa0 = *(const half8*)(pw + jl*P_RS + 8*h);
            const half8 pa1 = *(const half8*)(pw + jl*P_RS + 16 + 8*h);
            #pragma unroll
            for (int nt = 0; nt < 8; ++nt) {
                const half8 vf0 = *(const half8*)(vbt + 1024*nt + vo0);
                const half8 vf1 = *(const half8*)(vbt + 1024*nt + vo1);
                // A=V (m=d), B=P (n=q): D[d][q] += V^T[d][k] P[q][k]
                o[nt] = __builtin_amdgcn_mfma_f32_32x32x16_f16(vf0, pa0, o[nt], 0,0,0);
                o[nt] = __builtin_amdgcn_mfma_f32_32x32x16_f16(vf1, pa1, o[nt], 0,0,0);
            }
        };

        __syncthreads();                                     // bar 0
        int pvb = 0;
        for (int t = 0; t < 64; ++t) {
            if (t > 0) { pv_step(t - 1, pvb); pvb = (pvb == 2) ? 0 : pvb + 1; }
            __syncthreads();                                 // bars 1..64
        }
        pv_step(63, pvb);                                    // 63 % 3 == 0
        __syncthreads();                                     // bar 65

        // coalesced store: out[b][32nt+row][i0+jl], lanes consecutive in jl
        const float oscl = oscb[strip][jl];
        #pragma unroll
        for (int nt = 0; nt < 8; ++nt) {
            #pragma unroll
            for (int r = 0; r < 16; ++r) {
                const int row = (r&3) + 8*(r>>2) + 4*h;
                ob[(size_t)(32*nt + row) * S_ + i0 + jl] = o[nt][r] * oscl;
            }
        }
    }
}

extern "C" void kernel_launch(void* const* d_in, const int* in_sizes, int n_in,
                              void* d_out, int out_size, void* d_ws, size_t ws_size,
                              hipStream_t stream)
{
    const float* q    = (const float*)d_in[0];
    const float* k    = (const float*)d_in[1];   // [B][D][S]
    const float* v    = (const float*)d_in[2];   // [B][S][D]
    const int*   mask = (const int*)d_in[3];
    float*       out  = (float*)d_out;

    _Float16* kt = (_Float16*)d_ws;               // [B][S][D] swizzled
    _Float16* vtp = kt + (size_t)B_ * S_ * D_;    // [B][D][S]

    // K: [256][2048] -> swizzled [2048][256]
    tr_swz<<<dim3(S_/64, D_/64, B_), dim3(256), 0, stream>>>(k, kt, D_, S_, 1);
    // V: [2048][256] -> [256][2048]
    tr_swz<<<dim3(D_/64, S_/64, B_), dim3(256), 0, stream>>>(v, vtp, S_, D_, 0);

    attn_v7<<<dim3(B_ * (S_/128)), dim3(512), 0, stream>>>(q, kt, vtp, mask, out);
}

// Round 4
// 293.426 us; speedup vs baseline: 2.3505x; 1.0396x over previous
//
#include <hip/hip_runtime.h>

typedef _Float16 half8 __attribute__((ext_vector_type(8)));
typedef float floatx16 __attribute__((ext_vector_type(16)));
typedef int int4v __attribute__((ext_vector_type(4)));

#define B_  16
#define S_  2048
#define D_  256
#define P_RS 40
#define LOG2E 1.4426950408889634f

#define DPP_ROR(x, n) __int_as_float(__builtin_amdgcn_update_dpp( \
    0, __float_as_int(x), 0x120 + (n), 0xf, 0xf, false))

__device__ __forceinline__ float rmax32(float x) {
    x = fmaxf(x, DPP_ROR(x, 1));
    x = fmaxf(x, DPP_ROR(x, 2));
    x = fmaxf(x, DPP_ROR(x, 4));
    x = fmaxf(x, DPP_ROR(x, 8));
    x = fmaxf(x, __shfl_xor(x, 16, 64));
    return x;
}
__device__ __forceinline__ float rsum32(float x) {
    x += DPP_ROR(x, 1);
    x += DPP_ROR(x, 2);
    x += DPP_ROR(x, 4);
    x += DPP_ROR(x, 8);
    x += __shfl_xor(x, 16, 64);
    return x;
}

// async 16B/lane global -> LDS DMA; lds base wave-uniform, HW adds lane*16
__device__ __forceinline__ void dma16(const _Float16* g, _Float16* l) {
    __builtin_amdgcn_global_load_lds(
        (const __attribute__((address_space(1))) void*)g,
        (__attribute__((address_space(3))) void*)l, 16, 0, 0);
}

// out[c][r] (f16) = in[r][c] (f32). If swz: 16B-chunk c' = (c&~7)|((c&7)^((row>>1)&7))
__device__ __forceinline__ void tr_body(const float* __restrict__ ib,
                                        _Float16* __restrict__ ob,
                                        int Rin, int Cin, int swz,
                                        int c0, int r0, _Float16* tl, int t)
{
    const int rr = t >> 4, cc = (t & 15) * 4;
    #pragma unroll
    for (int p = 0; p < 4; ++p) {
        const float4 x = *(const float4*)(ib + (size_t)(r0 + rr + 16*p) * Cin + c0 + cc);
        tl[(cc+0)*72 + rr + 16*p] = (_Float16)x.x;
        tl[(cc+1)*72 + rr + 16*p] = (_Float16)x.y;
        tl[(cc+2)*72 + rr + 16*p] = (_Float16)x.z;
        tl[(cc+3)*72 + rr + 16*p] = (_Float16)x.w;
    }
    __syncthreads();
    #pragma unroll
    for (int u = 0; u < 2; ++u) {
        const int idx  = t + 256*u;
        const int jloc = idx >> 3, lc = idx & 7;
        const half8 h = *(const half8*)(tl + jloc*72 + 8*lc);
        const int jg  = c0 + jloc;
        const int lco = swz ? (lc ^ ((jg >> 1) & 7)) : lc;
        *(half8*)(ob + (size_t)jg * Rin + r0 + 8*lco) = h;
    }
}

// Both transposes fused into one launch (saves one kernel dispatch).
// id: [0,2048) = K tiles (swz), [2048,4096) = V tiles.
__global__ __launch_bounds__(256)
void tr_both(const float* __restrict__ k, const float* __restrict__ v,
             _Float16* __restrict__ kt, _Float16* __restrict__ vtp)
{
    __shared__ _Float16 tl[64 * 72];
    const int id   = blockIdx.x;
    const int isV  = id >> 11;
    const int rem  = id & 2047;
    const int z    = rem >> 7;
    const int t128 = rem & 127;
    if (!isV) {
        const int c0 = (t128 & 31) * 64, r0 = (t128 >> 5) * 64;
        tr_body(k + (size_t)z * D_ * S_, kt + (size_t)z * S_ * D_,
                D_, S_, 1, c0, r0, tl, threadIdx.x);
    } else {
        const int c0 = (t128 & 3) * 64, r0 = (t128 >> 2) * 64;
        tr_body(v + (size_t)z * S_ * D_, vtp + (size_t)z * S_ * D_,
                S_, D_, 0, c0, r0, tl, threadIdx.x);
    }
}

// v8: counted-vmcnt pipeline (T3/T4). The v4..v7 invariant (~4-7K cyc/tile
// per CU regardless of wave structure) is the __syncthreads vmcnt(0) drain:
// every tile's DMA prefetch was forced to land inside its own tile, so tile
// time = DMA round trip, not compute. Fix per m201 template: raw s_barrier
// with counted s_waitcnt vmcnt(4) in the SAME asm block, depth-2 prefetch
// (issue K/V for t+2; the 4 in-flight survivors are t+2's, so t+1's have
// landed). K tri-buffered, V quad-buffered. V staging moved to consumer
// waves (balances issue). Mask pre-staged to LDS so producer vmcnt counts
// ONLY its 4 K-DMAs. setprio(1) around both MFMA clusters (T5: pays with
// role-diverse waves). All waves drain vmcnt(0) pre-exit (stale wrapped
// DMAs must not land after LDS dealloc).
__global__ __launch_bounds__(512, 2)
void attn_v8(const float* __restrict__ q, const _Float16* __restrict__ kts,
             const _Float16* __restrict__ vt, const int* __restrict__ mask,
             float* __restrict__ out)
{
    __shared__ _Float16 kb[3][32 * D_];          // 48 KB K tiles
    __shared__ _Float16 vb[4][32 * D_];          // 64 KB V tiles [256 d][32 k] swz
    __shared__ _Float16 pbuf[4][2][32 * P_RS];   // 20 KB P strips
    __shared__ float    mlds[S_];                // 8 KB mask offsets
    __shared__ float    alb [4][2][32];
    __shared__ float    oscb[4][32];
    __shared__ int      flg [4][2];

    const int tid   = threadIdx.x;
    const int w     = tid >> 6;
    const int isC   = w >> 2;                // 0 = producer, 1 = consumer
    const int strip = w & 3;
    const int lane  = tid & 63;
    const int jl    = lane & 31;
    const int h     = lane >> 5;
    const int pj    = (jl >> 1) & 7;

    // XCD swizzle: each XCD owns 2 batches x 16 row-groups
    const int bx   = blockIdx.x;
    const int rest = bx >> 3;
    const int b    = 2 * (bx & 7) + (rest >> 4);
    const int qg   = rest & 15;
    const int i0   = qg * 128 + 32 * strip;

    const float*    qb  = q    + (size_t)b * S_ * D_;
    const _Float16* ktb = kts  + (size_t)b * S_ * D_;   // [S][D] swizzled
    const _Float16* vtb = vt   + (size_t)b * S_ * D_;   // [D][S]
    const int*      mb  = mask + (size_t)b * S_;
    float*          ob  = out  + (size_t)b * D_ * S_;

    // cooperative mask -> LDS (so producer vmcnt tracks only K-DMAs)
    {
        const int4v mi = *(const int4v*)(mb + 4*tid);
        mlds[4*tid+0] = mi[0] ? 0.0f : -1.0e9f;
        mlds[4*tid+1] = mi[1] ? 0.0f : -1.0e9f;
        mlds[4*tid+2] = mi[2] ? 0.0f : -1.0e9f;
        mlds[4*tid+3] = mi[3] ? 0.0f : -1.0e9f;
    }

    if (!isC) {
        // ================= producer: QK^T + online softmax =================
        half8 qf[16];
        {
            const float* qrow = qb + (size_t)(i0 + jl) * D_;
            #pragma unroll
            for (int s = 0; s < 16; ++s) {
                const float4 a = *(const float4*)(qrow + 16*s + 8*h);
                const float4 c = *(const float4*)(qrow + 16*s + 8*h + 4);
                half8 v;
                v[0]=(_Float16)a.x; v[1]=(_Float16)a.y; v[2]=(_Float16)a.z; v[3]=(_Float16)a.w;
                v[4]=(_Float16)c.x; v[5]=(_Float16)c.y; v[6]=(_Float16)c.z; v[7]=(_Float16)c.w;
                qf[s] = v;
            }
        }
        float M[16], lsum[16];
        #pragma unroll
        for (int r = 0; r < 16; ++r) { M[r] = -3.0e38f; lsum[r] = 0.0f; }

        // prologue: K(0) -> kb[0], K(1) -> kb[1]  (wave stages rows 8s..8s+7)
        #pragma unroll
        for (int m = 0; m < 4; ++m)
            dma16(ktb + (size_t)(8*strip + 2*m) * D_ + lane*8,
                  kb[0] + (8*strip + 2*m) * D_);
        #pragma unroll
        for (int m = 0; m < 4; ++m)
            dma16(ktb + (size_t)(32 + 8*strip + 2*m) * D_ + lane*8,
                  kb[1] + (8*strip + 2*m) * D_);
        asm volatile("s_waitcnt vmcnt(4) lgkmcnt(0)\n\ts_barrier" ::: "memory");

        int kc = 0, kp = 2;                      // kb idx of K(t) / K(t+2) dest
        for (int t = 0; t < 64; ++t) {
            const int jexp = ((t + 2) & 63) * 32;   // wraps harmlessly at end

            // prefetch K(t+2); stays in flight across 2 barriers (vmcnt(4))
            _Float16* kd = kb[kp];
            #pragma unroll
            for (int m = 0; m < 4; ++m)
                dma16(ktb + (size_t)(jexp + 8*strip + 2*m) * D_ + lane*8,
                      kd + (8*strip + 2*m) * D_);

            const float mo = mlds[32*t + jl];
            const _Float16* kcur = kb[kc];

            floatx16 sa = (floatx16){}, sb = (floatx16){};
            __builtin_amdgcn_s_setprio(1);
            #pragma unroll
            for (int s = 0; s < 16; s += 2) {
                const half8 k0 = *(const half8*)(kcur + jl*D_ + 8*((2*s     + h) ^ pj));
                const half8 k1 = *(const half8*)(kcur + jl*D_ + 8*((2*s + 2 + h) ^ pj));
                sa = __builtin_amdgcn_mfma_f32_32x32x16_f16(qf[s],   k0, sa, 0,0,0);
                sb = __builtin_amdgcn_mfma_f32_32x32x16_f16(qf[s+1], k1, sb, 0,0,0);
            }
            __builtin_amdgcn_s_setprio(0);
            float sv[16];
            #pragma unroll
            for (int r = 0; r < 16; ++r) sv[r] = sa[r] + sb[r] + mo;

            // lazy online max: rescale only when some row exceeds M by >8
            float mx = sv[0] - M[0];
            #pragma unroll
            for (int r = 1; r < 16; ++r) mx = fmaxf(mx, sv[r] - M[r]);
            const bool resc = __any(mx > 8.0f);
            if (resc) {
                #pragma unroll
                for (int r = 0; r < 16; ++r) {
                    const float tm = rmax32(sv[r]);
                    const float Mn = fmaxf(M[r], tm);
                    const float al = __builtin_amdgcn_exp2f((M[r] - Mn) * LOG2E);
                    M[r] = Mn;
                    lsum[r] *= al;
                    if (jl == 0) alb[strip][t & 1][(r&3) + 8*(r>>2) + 4*h] = al;
                }
            }
            if (lane == 0) flg[strip][t & 1] = resc ? 1 : 0;

            // p = e^(sv-M) (<= e^8, f16-safe); publish P strip
            _Float16* pw = pbuf[strip][t & 1];
            #pragma unroll
            for (int r = 0; r < 16; ++r) {
                const float p = __builtin_amdgcn_exp2f((sv[r] - M[r]) * LOG2E);
                lsum[r] += p;
                pw[((r&3) + 8*(r>>2) + 4*h) * P_RS + jl] = (_Float16)p;
            }

            // counted wait: own 4 newest (t+2's K) stay in flight; t+1's landed
            asm volatile("s_waitcnt vmcnt(4) lgkmcnt(0)\n\ts_barrier" ::: "memory");
            kc = (kc == 2) ? 0 : kc + 1;
            kp = (kp == 2) ? 0 : kp + 1;
        }

        // epilogue: final per-row scale 1/(16*l) -> LDS for the consumer
        #pragma unroll
        for (int r = 0; r < 16; ++r) {
            const float osc = 1.0f / (16.0f * rsum32(lsum[r]));
            if (jl == 0) oscb[strip][(r&3) + 8*(r>>2) + 4*h] = osc;
        }
        asm volatile("s_waitcnt lgkmcnt(0)\n\ts_barrier" ::: "memory");
        asm volatile("s_waitcnt vmcnt(0)" ::: "memory");   // stale wrapped DMAs
    } else {
        // ============ consumer: V staging + PV, one tile behind ============
        // V-DMA lane constants: storage chunk q' = lane&7 at pair-group
        // g0+(lane>>3); source chunk q = q'^(g&7).
        const int qv  = (lane & 7) ^ ((lane >> 3) & 7);
        const int vdr = 2 * (lane >> 3) + (qv >> 2);
        const int vco = 8 * (qv & 3);
        const _Float16* vsrc = vtb + (size_t)(64*strip + vdr) * S_ + vco;

        // V read offsets: pair-group g = 16nt+(jl>>1); chunk x stored at x^(g&7)
        const int gb  = jl >> 1;
        const int swz = gb & 7;
        const int x0  = 4*(jl & 1) + h;
        const int vo0 = gb*64 + ((x0    ) ^ swz)*8;
        const int vo1 = gb*64 + ((x0 ^ 2) ^ swz)*8;

        floatx16 o[8];
        #pragma unroll
        for (int nt = 0; nt < 8; ++nt) o[nt] = (floatx16){};

        auto pv_step = [&](int tt, const _Float16* vbt) {
            const int buf = tt & 1;
            if (flg[strip][buf]) {
                const float al = alb[strip][buf][jl];
                #pragma unroll
                for (int nt = 0; nt < 8; ++nt)
                    #pragma unroll
                    for (int r = 0; r < 16; ++r) o[nt][r] *= al;
            }
            const _Float16* pw  = pbuf[strip][buf];
            const half8 pa0 = *(const half8*)(pw + jl*P_RS + 8*h);
            const half8 pa1 = *(const half8*)(pw + jl*P_RS + 16 + 8*h);
            __builtin_amdgcn_s_setprio(1);
            #pragma unroll
            for (int nt = 0; nt < 8; ++nt) {
                const half8 vf0 = *(const half8*)(vbt + 1024*nt + vo0);
                const half8 vf1 = *(const half8*)(vbt + 1024*nt + vo1);
                // A=V (m=d), B=P (n=q): D[d][q] += V^T[d][k] P[q][k]
                o[nt] = __builtin_amdgcn_mfma_f32_32x32x16_f16(vf0, pa0, o[nt], 0,0,0);
                o[nt] = __builtin_amdgcn_mfma_f32_32x32x16_f16(vf1, pa1, o[nt], 0,0,0);
            }
            __builtin_amdgcn_s_setprio(0);
        };

        // prologue: V(0) -> vb[0], V(1) -> vb[1]
        #pragma unroll
        for (int m = 0; m < 4; ++m)
            dma16(vsrc + (size_t)(16*m) * S_,      vb[0] + 2048*strip + 512*m);
        #pragma unroll
        for (int m = 0; m < 4; ++m)
            dma16(vsrc + 32 + (size_t)(16*m) * S_, vb[1] + 2048*strip + 512*m);
        asm volatile("s_waitcnt vmcnt(4) lgkmcnt(0)\n\ts_barrier" ::: "memory");

        for (int t = 0; t < 64; ++t) {
            const int jexp = ((t + 2) & 63) * 32;

            // prefetch V(t+2)
            _Float16* vd = vb[(t + 2) & 3];
            #pragma unroll
            for (int m = 0; m < 4; ++m)
                dma16(vsrc + jexp + (size_t)(16*m) * S_, vd + 2048*strip + 512*m);

            if (t > 0) pv_step(t - 1, vb[(t - 1) & 3]);

            asm volatile("s_waitcnt vmcnt(4) lgkmcnt(0)\n\ts_barrier" ::: "memory");
        }
        pv_step(63, vb[63 & 3]);
        asm volatile("s_waitcnt lgkmcnt(0)\n\ts_barrier" ::: "memory");

        // coalesced store: out[b][32nt+row][i0+jl]
        const float oscl = oscb[strip][jl];
        #pragma unroll
        for (int nt = 0; nt < 8; ++nt) {
            #pragma unroll
            for (int r = 0; r < 16; ++r) {
                const int row = (r&3) + 8*(r>>2) + 4*h;
                ob[(size_t)(32*nt + row) * S_ + i0 + jl] = o[nt][r] * oscl;
            }
        }
        asm volatile("s_waitcnt vmcnt(0)" ::: "memory");   // stale wrapped DMAs
    }
}

extern "C" void kernel_launch(void* const* d_in, const int* in_sizes, int n_in,
                              void* d_out, int out_size, void* d_ws, size_t ws_size,
                              hipStream_t stream)
{
    const float* q    = (const float*)d_in[0];
    const float* k    = (const float*)d_in[1];   // [B][D][S]
    const float* v    = (const float*)d_in[2];   // [B][S][D]
    const int*   mask = (const int*)d_in[3];
    float*       out  = (float*)d_out;

    _Float16* kt = (_Float16*)d_ws;               // [B][S][D] swizzled
    _Float16* vtp = kt + (size_t)B_ * S_ * D_;    // [B][D][S]

    tr_both<<<dim3(4096), dim3(256), 0, stream>>>(k, v, kt, vtp);
    attn_v8<<<dim3(B_ * (S_/128)), dim3(512), 0, stream>>>(q, kt, vtp, mask, out);
}

// Round 8
// 280.750 us; speedup vs baseline: 2.4566x; 1.0451x over previous
//
#include <hip/hip_runtime.h>

typedef _Float16 half8 __attribute__((ext_vector_type(8)));
typedef float floatx16 __attribute__((ext_vector_type(16)));

#define B_  16
#define S_  2048
#define D_  256
#define LOG2E 1.4426950408889634f

// async 16B/lane global -> LDS DMA; lds base wave-uniform, HW adds lane*16
__device__ __forceinline__ void dma16(const _Float16* g, _Float16* l) {
    __builtin_amdgcn_global_load_lds(
        (const __attribute__((address_space(1))) void*)g,
        (__attribute__((address_space(3))) void*)l, 16, 0, 0);
}

// out[c][r] (f16) = in[r][c] (f32). If swz: 16B-chunk c' = (c&~7)|((c&7)^((row>>1)&7))
__device__ __forceinline__ void tr_body(const float* __restrict__ ib,
                                        _Float16* __restrict__ ob,
                                        int Rin, int Cin, int swz,
                                        int c0, int r0, _Float16* tl, int t)
{
    const int rr = t >> 4, cc = (t & 15) * 4;
    #pragma unroll
    for (int p = 0; p < 4; ++p) {
        const float4 x = *(const float4*)(ib + (size_t)(r0 + rr + 16*p) * Cin + c0 + cc);
        tl[(cc+0)*72 + rr + 16*p] = (_Float16)x.x;
        tl[(cc+1)*72 + rr + 16*p] = (_Float16)x.y;
        tl[(cc+2)*72 + rr + 16*p] = (_Float16)x.z;
        tl[(cc+3)*72 + rr + 16*p] = (_Float16)x.w;
    }
    __syncthreads();
    #pragma unroll
    for (int u = 0; u < 2; ++u) {
        const int idx  = t + 256*u;
        const int jloc = idx >> 3, lc = idx & 7;
        const half8 h = *(const half8*)(tl + jloc*72 + 8*lc);
        const int jg  = c0 + jloc;
        const int lco = swz ? (lc ^ ((jg >> 1) & 7)) : lc;
        *(half8*)(ob + (size_t)jg * Rin + r0 + 8*lco) = h;
    }
}

__global__ __launch_bounds__(256)
void tr_both(const float* __restrict__ k, const float* __restrict__ v,
             _Float16* __restrict__ kt, _Float16* __restrict__ vtp)
{
    __shared__ _Float16 tl[64 * 72];
    const int id   = blockIdx.x;
    const int isV  = id >> 11;
    const int rem  = id & 2047;
    const int z    = rem >> 7;
    const int t128 = rem & 127;
    if (!isV) {
        const int c0 = (t128 & 31) * 64, r0 = (t128 >> 5) * 64;
        tr_body(k + (size_t)z * D_ * S_, kt + (size_t)z * S_ * D_,
                D_, S_, 1, c0, r0, tl, threadIdx.x);
    } else {
        const int c0 = (t128 & 3) * 64, r0 = (t128 >> 2) * 64;
        tr_body(v + (size_t)z * S_ * D_, vtp + (size_t)z * S_ * D_,
                S_, D_, 0, c0, r0, tl, threadIdx.x);
    }
}

// v10 = v9 with two fixes:
// (1) mask added to sv BEFORE the row max (v4 semantics): M now tracks the
//     MASKED max, so live p >= e^-8 -> f16-safe. v9 tracked the unmasked
//     max; rows where unmasked-max >> masked-max had all live P underflow
//     f16 in the PV convert while f32 lsum stayed accurate -> absmax 0.238.
// (2) h-half P exchange via __shfl_xor(x,32,64)+select instead of
//     permlane32_swap (correct regardless of that builtin's dst/src and
//     return-order convention; re-optimize later once layout is pinned).
// Structure unchanged: S^T = mfma(K,Q) -> one q-row per lane, in-register
// softmax (per-lane scalars M/lsum, 1 exp-rescale), in-register P repack
// -> PV B-operand, O = mfma(V^T,P^T) -> coalesced store. 8 waves =
// 4 q-strips x 2 kv-halves, in-block merge via dead K/V LDS.
__global__ __launch_bounds__(512, 2)
void attn_v10(const float* __restrict__ q, const _Float16* __restrict__ kts,
              const _Float16* __restrict__ vt, const int* __restrict__ mask,
              float* __restrict__ out)
{
    __shared__ _Float16 kb[2][2][32 * D_];   // 64 KB [half][buf] K tiles (swz rows)
    __shared__ _Float16 vb[2][2][D_ * 32];   // 64 KB [half][buf] V^T rows (chunk-swz)
    __shared__ float    mneg[2048];          //  8 KB [(tg*2+h)*16 + r] 0 / -1e9
    __shared__ float    statM[4*32], statL[4*32];

    const int tid   = threadIdx.x;
    const int w     = tid >> 6;
    const int strip = w & 3;                 // q strip within block
    const int half  = w >> 2;                // kv half (0: kv 0..1023, 1: 1024..2047)
    const int lane  = tid & 63;
    const int jl    = lane & 31;
    const int h     = lane >> 5;
    const int pj    = (jl >> 1) & 7;

    // XCD swizzle: each XCD owns 2 batches x 16 row-groups
    const int bx   = blockIdx.x;
    const int rest = bx >> 3;
    const int b    = 2 * (bx & 7) + (rest >> 4);
    const int qg   = rest & 15;
    const int i0   = qg * 128 + 32 * strip;  // this wave's 32 q rows

    const float*    qb  = q    + (size_t)b * S_ * D_;
    const _Float16* ktb = kts  + (size_t)b * S_ * D_;   // [S][D] swizzled
    const _Float16* vtb = vt   + (size_t)b * S_ * D_;   // [D][S]
    const int*      mb  = mask + (size_t)b * S_;
    float*          ob  = out  + (size_t)b * D_ * S_;

    // mask table: mneg[(tg*2+hh)*16 + r] = mask[32*tg + (r&3)+8*(r>>2)+4*hh]
    #pragma unroll
    for (int u = 0; u < 4; ++u) {
        const int i  = tid + 512*u;
        const int tg = i >> 5, hh = (i >> 4) & 1, r = i & 15;
        const int kv = 32*tg + (r&3) + 8*(r>>2) + 4*hh;
        mneg[i] = mb[kv] ? 0.0f : -1.0e9f;
    }

    // Q B-frags: B[k=16s+8h+j][q=i0+jl]
    half8 qf[16];
    {
        const float* qrow = qb + (size_t)(i0 + jl) * D_;
        #pragma unroll
        for (int s = 0; s < 16; ++s) {
            const float4 a = *(const float4*)(qrow + 16*s + 8*h);
            const float4 c = *(const float4*)(qrow + 16*s + 8*h + 4);
            half8 v;
            v[0]=(_Float16)a.x; v[1]=(_Float16)a.y; v[2]=(_Float16)a.z; v[3]=(_Float16)a.w;
            v[4]=(_Float16)c.x; v[5]=(_Float16)c.y; v[6]=(_Float16)c.z; v[7]=(_Float16)c.w;
            qf[s] = v;
        }
    }

    floatx16 o[8];
    #pragma unroll
    for (int nt = 0; nt < 8; ++nt) o[nt] = (floatx16){};
    float M = -3.0e38f, lsum = 0.0f;

    // V-DMA lane constants (source pre-swizzle; LDS dest linear):
    // dest row = base + (lane>>2), chunk c' = lane&3 stores src chunk c'^(row&3)
    const int vrow = lane >> 2;
    const int vco  = 8 * ((lane & 3) ^ (vrow & 3));
    // V read offsets: chunk (2s+h)^(row&3), row = 32nt+jl
    const int vo0 = jl*32 + (((0 + h) ^ (jl & 3)) * 8);
    const int vo1 = jl*32 + (((2 + h) ^ (jl & 3)) * 8);

    const int j0base = half * 1024;

    auto stage = [&](int tile, int buf) {
        const int j0 = j0base + tile * 32;
        _Float16* kd = kb[half][buf];
        #pragma unroll
        for (int m = 0; m < 4; ++m)
            dma16(ktb + (size_t)(j0 + 8*strip + 2*m) * D_ + lane*8,
                  kd + (8*strip + 2*m) * D_);
        _Float16* vd = vb[half][buf];
        #pragma unroll
        for (int m = 0; m < 4; ++m)
            dma16(vtb + (size_t)(64*strip + 16*m + vrow) * S_ + j0 + vco,
                  vd + (64*strip + 16*m) * 32);
    };

    auto pkf = [](float a, float bf) -> int {
        auto t = __builtin_amdgcn_cvt_pkrtz(a, bf);   // __fp16 ext_vector(2)
        return __builtin_bit_cast(int, t);
    };
    // h-half exchange: lo word = h ? partner(b) : a ; hi word = h ? b : partner(a)
    auto xsw = [&](int a, int bf, int& lo, int& hi) {
        const int ax = __shfl_xor(a, 32, 64);
        const int bx = __shfl_xor(bf, 32, 64);
        lo = h ? bx : a;
        hi = h ? bf : ax;
    };

    stage(0, 0);
    asm volatile("s_waitcnt vmcnt(0) lgkmcnt(0)\n\ts_barrier" ::: "memory");

    for (int tt = 0; tt < 32; ++tt) {
        if (tt < 31) stage(tt + 1, (tt + 1) & 1);

        const _Float16* kc = kb[half][tt & 1];
        const _Float16* vc = vb[half][tt & 1];
        const int tg = half*32 + tt;

        // S^T = K Q : A=K[kv=jl][16s+8h+j], B=Q-frag; two accumulation chains
        floatx16 sa = (floatx16){}, sb = (floatx16){};
        __builtin_amdgcn_s_setprio(1);
        #pragma unroll
        for (int s = 0; s < 16; s += 2) {
            const half8 k0 = *(const half8*)(kc + jl*D_ + 8*((2*s     + h) ^ pj));
            const half8 k1 = *(const half8*)(kc + jl*D_ + 8*((2*s + 2 + h) ^ pj));
            sa = __builtin_amdgcn_mfma_f32_32x32x16_f16(k0, qf[s],   sa, 0,0,0);
            sb = __builtin_amdgcn_mfma_f32_32x32x16_f16(k1, qf[s+1], sb, 0,0,0);
        }
        __builtin_amdgcn_s_setprio(0);

        // sv = scores + mask (BEFORE max: M must track the MASKED max)
        const float4* mrow = (const float4*)(mneg + (tg*2 + h)*16);
        const float4 m0 = mrow[0], m1 = mrow[1], m2 = mrow[2], m3 = mrow[3];
        float sv[16];
        sv[0]=sa[0]+sb[0]+m0.x;  sv[1]=sa[1]+sb[1]+m0.y;
        sv[2]=sa[2]+sb[2]+m0.z;  sv[3]=sa[3]+sb[3]+m0.w;
        sv[4]=sa[4]+sb[4]+m1.x;  sv[5]=sa[5]+sb[5]+m1.y;
        sv[6]=sa[6]+sb[6]+m1.z;  sv[7]=sa[7]+sb[7]+m1.w;
        sv[8]=sa[8]+sb[8]+m2.x;  sv[9]=sa[9]+sb[9]+m2.y;
        sv[10]=sa[10]+sb[10]+m2.z; sv[11]=sa[11]+sb[11]+m2.w;
        sv[12]=sa[12]+sb[12]+m3.x; sv[13]=sa[13]+sb[13]+m3.y;
        sv[14]=sa[14]+sb[14]+m3.z; sv[15]=sa[15]+sb[15]+m3.w;

        // lazy per-lane online max (q-row = jl; sync across h-partner)
        float c0 = fmaxf(fmaxf(fmaxf(sv[0],sv[1]),fmaxf(sv[2],sv[3])),
                         fmaxf(fmaxf(sv[4],sv[5]),fmaxf(sv[6],sv[7])));
        float c1 = fmaxf(fmaxf(fmaxf(sv[8],sv[9]),fmaxf(sv[10],sv[11])),
                         fmaxf(fmaxf(sv[12],sv[13]),fmaxf(sv[14],sv[15])));
        float cm = fmaxf(c0, c1);
        cm = fmaxf(cm, __shfl_xor(cm, 32, 64));
        if (__any(cm > M + 8.0f)) {
            const float Mn = fmaxf(M, cm);
            const float al = __builtin_amdgcn_exp2f((M - Mn) * LOG2E);
            M = Mn; lsum *= al;
            #pragma unroll
            for (int nt = 0; nt < 8; ++nt)
                #pragma unroll
                for (int r = 0; r < 16; ++r) o[nt][r] *= al;
        }

        // p = e^(sv-M) (<= e^8, f16-safe; masked -> 0); per-lane row sum
        float p[16];
        #pragma unroll
        for (int r = 0; r < 16; ++r)
            p[r] = __builtin_amdgcn_exp2f((sv[r] - M) * LOG2E);
        lsum += (((p[0]+p[1])+(p[2]+p[3]))+((p[4]+p[5])+(p[6]+p[7])))
              + (((p[8]+p[9])+(p[10]+p[11]))+((p[12]+p[13])+(p[14]+p[15])));

        // pack P^T B-frags: exchange pair words across h halves
        union H8 { int i[4]; half8 h8; } pa0u, pa1u;
        xsw(pkf(p[0],p[1]),   pkf(p[4],p[5]),   pa0u.i[0], pa0u.i[2]);
        xsw(pkf(p[2],p[3]),   pkf(p[6],p[7]),   pa0u.i[1], pa0u.i[3]);
        xsw(pkf(p[8],p[9]),   pkf(p[12],p[13]), pa1u.i[0], pa1u.i[2]);
        xsw(pkf(p[10],p[11]), pkf(p[14],p[15]), pa1u.i[1], pa1u.i[3]);

        // O += V^T P^T : A=V^T[d=32nt+jl][16s+8h+j], B=P^T
        __builtin_amdgcn_s_setprio(1);
        #pragma unroll
        for (int nt = 0; nt < 8; ++nt) {
            const half8 vf0 = *(const half8*)(vc + nt*1024 + vo0);
            const half8 vf1 = *(const half8*)(vc + nt*1024 + vo1);
            o[nt] = __builtin_amdgcn_mfma_f32_32x32x16_f16(vf0, pa0u.h8, o[nt], 0,0,0);
            o[nt] = __builtin_amdgcn_mfma_f32_32x32x16_f16(vf1, pa1u.h8, o[nt], 0,0,0);
        }
        __builtin_amdgcn_s_setprio(0);

        asm volatile("s_waitcnt vmcnt(0) lgkmcnt(0)\n\ts_barrier" ::: "memory");
    }

    // ---- in-block merge of kv halves (K/V LDS is dead scratch now) ----
    const float lT = lsum + __shfl_xor(lsum, 32, 64);
    float* ms = (strip < 2) ? ((float*)kb + strip * 8192)
                            : ((float*)vb + (strip - 2) * 8192);
    if (half == 1) {
        #pragma unroll
        for (int nt = 0; nt < 8; ++nt)
            #pragma unroll
            for (int r = 0; r < 16; ++r)
                ms[(nt*16 + r)*64 + lane] = o[nt][r];
        if (h == 0) { statM[strip*32 + jl] = M; statL[strip*32 + jl] = lT; }
    }
    __syncthreads();
    if (half == 0) {
        const float MB = statM[strip*32 + jl];
        const float lB = statL[strip*32 + jl];
        const float Mm = fmaxf(M, MB);
        const float aA = __builtin_amdgcn_exp2f((M  - Mm) * LOG2E);
        const float aB = __builtin_amdgcn_exp2f((MB - Mm) * LOG2E);
        const float osc = 1.0f / (16.0f * (aA*lT + aB*lB));
        #pragma unroll
        for (int nt = 0; nt < 8; ++nt) {
            #pragma unroll
            for (int r = 0; r < 16; ++r) {
                const int d = 32*nt + (r&3) + 8*(r>>2) + 4*h;
                ob[(size_t)d * S_ + i0 + jl] =
                    (aA*o[nt][r] + aB*ms[(nt*16 + r)*64 + lane]) * osc;
            }
        }
    }
}

extern "C" void kernel_launch(void* const* d_in, const int* in_sizes, int n_in,
                              void* d_out, int out_size, void* d_ws, size_t ws_size,
                              hipStream_t stream)
{
    const float* q    = (const float*)d_in[0];
    const float* k    = (const float*)d_in[1];   // [B][D][S]
    const float* v    = (const float*)d_in[2];   // [B][S][D]
    const int*   mask = (const int*)d_in[3];
    float*       out  = (float*)d_out;

    _Float16* kt  = (_Float16*)d_ws;              // [B][S][D] swizzled
    _Float16* vtp = kt + (size_t)B_ * S_ * D_;    // [B][D][S]

    tr_both<<<dim3(4096), dim3(256), 0, stream>>>(k, v, kt, vtp);
    attn_v10<<<dim3(B_ * (S_/128)), dim3(512), 0, stream>>>(q, kt, vtp, mask, out);
}

// Round 9
// 266.648 us; speedup vs baseline: 2.5866x; 1.0529x over previous
//
#include <hip/hip_runtime.h>

typedef _Float16 half8 __attribute__((ext_vector_type(8)));
typedef float floatx16 __attribute__((ext_vector_type(16)));

#define B_  16
#define S_  2048
#define D_  256
#define LOG2E 1.4426950408889634f

// async 16B/lane global -> LDS DMA; lds base wave-uniform, HW adds lane*16
__device__ __forceinline__ void dma16(const _Float16* g, _Float16* l) {
    __builtin_amdgcn_global_load_lds(
        (const __attribute__((address_space(1))) void*)g,
        (__attribute__((address_space(3))) void*)l, 16, 0, 0);
}

// out[c][r] (f16) = in[r][c] (f32). If swz: 16B-chunk c' = (c&~7)|((c&7)^(row&7))
// (period-8 row swizzle: K reads with pj=jl&7 land on 8 distinct bank-quads
// per 8-lane service group — v10's (row>>1)&7 gave only 4 -> 2-way conflict)
__device__ __forceinline__ void tr_body(const float* __restrict__ ib,
                                        _Float16* __restrict__ ob,
                                        int Rin, int Cin, int swz,
                                        int c0, int r0, _Float16* tl, int t)
{
    const int rr = t >> 4, cc = (t & 15) * 4;
    #pragma unroll
    for (int p = 0; p < 4; ++p) {
        const float4 x = *(const float4*)(ib + (size_t)(r0 + rr + 16*p) * Cin + c0 + cc);
        tl[(cc+0)*72 + rr + 16*p] = (_Float16)x.x;
        tl[(cc+1)*72 + rr + 16*p] = (_Float16)x.y;
        tl[(cc+2)*72 + rr + 16*p] = (_Float16)x.z;
        tl[(cc+3)*72 + rr + 16*p] = (_Float16)x.w;
    }
    __syncthreads();
    #pragma unroll
    for (int u = 0; u < 2; ++u) {
        const int idx  = t + 256*u;
        const int jloc = idx >> 3, lc = idx & 7;
        const half8 h = *(const half8*)(tl + jloc*72 + 8*lc);
        const int jg  = c0 + jloc;
        const int lco = swz ? (lc ^ (jg & 7)) : lc;
        *(half8*)(ob + (size_t)jg * Rin + r0 + 8*lco) = h;
    }
}

__global__ __launch_bounds__(256)
void tr_both(const float* __restrict__ k, const float* __restrict__ v,
             _Float16* __restrict__ kt, _Float16* __restrict__ vtp)
{
    __shared__ _Float16 tl[64 * 72];
    const int id   = blockIdx.x;
    const int isV  = id >> 11;
    const int rem  = id & 2047;
    const int z    = rem >> 7;
    const int t128 = rem & 127;
    if (!isV) {
        const int c0 = (t128 & 31) * 64, r0 = (t128 >> 5) * 64;
        tr_body(k + (size_t)z * D_ * S_, kt + (size_t)z * S_ * D_,
                D_, S_, 1, c0, r0, tl, threadIdx.x);
    } else {
        const int c0 = (t128 & 3) * 64, r0 = (t128 >> 2) * 64;
        tr_body(v + (size_t)z * S_ * D_, vtp + (size_t)z * S_ * D_,
                S_, D_, 0, c0, r0, tl, threadIdx.x);
    }
}

// v11 = v10 + (1) true conflict-free K/V bank swizzles (period-8; v10's were
// 2-way-conflicted, SQ_LDS_BANK_CONFLICT 16.8M), (2) PV pipelined one tile
// behind: tile t = {stageK(t+1); QK(t); PV(t-1); SM(t) overlapping PV exec;
// bar#1; stageV(t+1) into freed slot; bar#2+vmcnt(4)} — the softmax serial
// chain hides under PV MFMA latency, V stays 2-buffered, counted vmcnt keeps
// V(t+1) in flight across the barrier, (3) single QK acc chain (same-acc
// MFMAs pipeline in HW) freeing 16 regs to pay for the pa double-state.
__global__ __launch_bounds__(512, 2)
void attn_v11(const float* __restrict__ q, const _Float16* __restrict__ kts,
              const _Float16* __restrict__ vt, const int* __restrict__ mask,
              float* __restrict__ out)
{
    __shared__ _Float16 kb[2][2][32 * D_];   // 64 KB [half][buf] K tiles (swz rows)
    __shared__ _Float16 vb[2][2][D_ * 32];   // 64 KB [half][buf] V^T rows (chunk-swz)
    __shared__ float    mneg[2048];          //  8 KB [(tg*2+h)*16 + r] 0 / -1e9
    __shared__ float    statM[4*32], statL[4*32];

    const int tid   = threadIdx.x;
    const int w     = tid >> 6;
    const int strip = w & 3;                 // q strip within block
    const int half  = w >> 2;                // kv half (0: kv 0..1023, 1: 1024..2047)
    const int lane  = tid & 63;
    const int jl    = lane & 31;
    const int h     = lane >> 5;
    const int pj    = jl & 7;                // K read swizzle (period 8)

    // XCD swizzle: each XCD owns 2 batches x 16 row-groups
    const int bx   = blockIdx.x;
    const int rest = bx >> 3;
    const int b    = 2 * (bx & 7) + (rest >> 4);
    const int qg   = rest & 15;
    const int i0   = qg * 128 + 32 * strip;  // this wave's 32 q rows

    const float*    qb  = q    + (size_t)b * S_ * D_;
    const _Float16* ktb = kts  + (size_t)b * S_ * D_;   // [S][D] swizzled
    const _Float16* vtb = vt   + (size_t)b * S_ * D_;   // [D][S]
    const int*      mb  = mask + (size_t)b * S_;
    float*          ob  = out  + (size_t)b * D_ * S_;

    // mask table: mneg[(tg*2+hh)*16 + r] = mask[32*tg + (r&3)+8*(r>>2)+4*hh]
    #pragma unroll
    for (int u = 0; u < 4; ++u) {
        const int i  = tid + 512*u;
        const int tg = i >> 5, hh = (i >> 4) & 1, r = i & 15;
        const int kv = 32*tg + (r&3) + 8*(r>>2) + 4*hh;
        mneg[i] = mb[kv] ? 0.0f : -1.0e9f;
    }

    // Q B-frags: B[k=16s+8h+j][q=i0+jl]
    half8 qf[16];
    {
        const float* qrow = qb + (size_t)(i0 + jl) * D_;
        #pragma unroll
        for (int s = 0; s < 16; ++s) {
            const float4 a = *(const float4*)(qrow + 16*s + 8*h);
            const float4 c = *(const float4*)(qrow + 16*s + 8*h + 4);
            half8 v;
            v[0]=(_Float16)a.x; v[1]=(_Float16)a.y; v[2]=(_Float16)a.z; v[3]=(_Float16)a.w;
            v[4]=(_Float16)c.x; v[5]=(_Float16)c.y; v[6]=(_Float16)c.z; v[7]=(_Float16)c.w;
            qf[s] = v;
        }
    }

    floatx16 o[8];
    #pragma unroll
    for (int nt = 0; nt < 8; ++nt) o[nt] = (floatx16){};
    float M = -3.0e38f, lsum = 0.0f;

    // V staging (source pre-swizzle; LDS dest linear): dest row r =
    // 64strip+16m+(lane>>2), dest chunk lane&3 holds src chunk
    // (lane&3)^((r>>1)&3) = (lane&3)^((lane>>3)&3).
    const int vrow = lane >> 2;
    const int vco  = 8 * ((lane & 3) ^ ((lane >> 3) & 3));
    // V read: row jl, chunkpos = l2 ^ ((jl>>1)&3) -> bank-quad
    // 4*(jl&1) + ((jl>>1)&3): all 8 quads per 8-lane group. l2 = 2ks+h.
    const int vo0 = jl*32 + 8*((0 + h) ^ ((jl >> 1) & 3));
    const int vo1 = jl*32 + 8*((2 + h) ^ ((jl >> 1) & 3));

    const int j0base = half * 1024;

    auto stageK = [&](int tile, int buf) {
        const int j0 = j0base + tile * 32;
        _Float16* kd = kb[half][buf];
        #pragma unroll
        for (int m = 0; m < 4; ++m)
            dma16(ktb + (size_t)(j0 + 8*strip + 2*m) * D_ + lane*8,
                  kd + (8*strip + 2*m) * D_);
    };
    auto stageV = [&](int tile, int buf) {
        const int j0 = j0base + tile * 32;
        _Float16* vd = vb[half][buf];
        #pragma unroll
        for (int m = 0; m < 4; ++m)
            dma16(vtb + (size_t)(64*strip + 16*m + vrow) * S_ + j0 + vco,
                  vd + (64*strip + 16*m) * 32);
    };

    auto pkf = [](float a, float bf) -> int {
        auto t = __builtin_amdgcn_cvt_pkrtz(a, bf);   // __fp16 ext_vector(2)
        return __builtin_bit_cast(int, t);
    };
    // h-half exchange: lo word = h ? partner(b) : a ; hi word = h ? b : partner(a)
    auto xsw = [&](int a, int bf, int& lo, int& hi) {
        const int ax = __shfl_xor(a, 32, 64);
        const int bx = __shfl_xor(bf, 32, 64);
        lo = h ? bx : a;
        hi = h ? bf : ax;
    };

    union H8 { int i[4]; half8 h8; };
    H8 paA0, paA1, paB0, paB1;               // prev / cur P fragments

    stageK(0, 0);
    stageV(0, 0);
    asm volatile("s_waitcnt vmcnt(0) lgkmcnt(0)\n\ts_barrier" ::: "memory");

    for (int tt = 0; tt < 32; ++tt) {
        if (tt < 31) stageK(tt + 1, (tt + 1) & 1);

        // ---- QK(t): single acc chain (same-acc MFMAs pipeline in HW) ----
        const _Float16* kc = kb[half][tt & 1];
        floatx16 sc = (floatx16){};
        __builtin_amdgcn_s_setprio(1);
        #pragma unroll
        for (int s = 0; s < 16; ++s) {
            const half8 k0 = *(const half8*)(kc + jl*D_ + 8*((2*s + h) ^ pj));
            sc = __builtin_amdgcn_mfma_f32_32x32x16_f16(k0, qf[s], sc, 0,0,0);
        }
        __builtin_amdgcn_s_setprio(0);

        // ---- PV(t-1): independent of QK(t); runs while QK executes ----
        if (tt > 0) {
            const _Float16* vc = vb[half][(tt - 1) & 1];
            __builtin_amdgcn_s_setprio(1);
            #pragma unroll
            for (int nt = 0; nt < 8; ++nt) {
                const half8 vf0 = *(const half8*)(vc + nt*1024 + vo0);
                const half8 vf1 = *(const half8*)(vc + nt*1024 + vo1);
                o[nt] = __builtin_amdgcn_mfma_f32_32x32x16_f16(vf0, paA0.h8, o[nt], 0,0,0);
                o[nt] = __builtin_amdgcn_mfma_f32_32x32x16_f16(vf1, paA1.h8, o[nt], 0,0,0);
            }
            __builtin_amdgcn_s_setprio(0);
        }

        // ---- SM(t): overlaps PV(t-1) execution ----
        const int tg = half*32 + tt;
        const float4* mrow = (const float4*)(mneg + (tg*2 + h)*16);
        const float4 m0 = mrow[0], m1 = mrow[1], m2 = mrow[2], m3 = mrow[3];
        float sv[16];
        sv[0]=sc[0]+m0.x;  sv[1]=sc[1]+m0.y;  sv[2]=sc[2]+m0.z;  sv[3]=sc[3]+m0.w;
        sv[4]=sc[4]+m1.x;  sv[5]=sc[5]+m1.y;  sv[6]=sc[6]+m1.z;  sv[7]=sc[7]+m1.w;
        sv[8]=sc[8]+m2.x;  sv[9]=sc[9]+m2.y;  sv[10]=sc[10]+m2.z; sv[11]=sc[11]+m2.w;
        sv[12]=sc[12]+m3.x; sv[13]=sc[13]+m3.y; sv[14]=sc[14]+m3.z; sv[15]=sc[15]+m3.w;

        float c0 = fmaxf(fmaxf(fmaxf(sv[0],sv[1]),fmaxf(sv[2],sv[3])),
                         fmaxf(fmaxf(sv[4],sv[5]),fmaxf(sv[6],sv[7])));
        float c1 = fmaxf(fmaxf(fmaxf(sv[8],sv[9]),fmaxf(sv[10],sv[11])),
                         fmaxf(fmaxf(sv[12],sv[13]),fmaxf(sv[14],sv[15])));
        float cm = fmaxf(c0, c1);
        cm = fmaxf(cm, __shfl_xor(cm, 32, 64));
        if (__any(cm > M + 8.0f)) {
            // rescale AFTER PV(t-1) was added (o and pa(t-1) share scale M_old)
            const float Mn = fmaxf(M, cm);
            const float al = __builtin_amdgcn_exp2f((M - Mn) * LOG2E);
            M = Mn; lsum *= al;
            #pragma unroll
            for (int nt = 0; nt < 8; ++nt)
                #pragma unroll
                for (int r = 0; r < 16; ++r) o[nt][r] *= al;
        }

        float p[16];
        #pragma unroll
        for (int r = 0; r < 16; ++r)
            p[r] = __builtin_amdgcn_exp2f((sv[r] - M) * LOG2E);
        lsum += (((p[0]+p[1])+(p[2]+p[3]))+((p[4]+p[5])+(p[6]+p[7])))
              + (((p[8]+p[9])+(p[10]+p[11]))+((p[12]+p[13])+(p[14]+p[15])));

        xsw(pkf(p[0],p[1]),   pkf(p[4],p[5]),   paB0.i[0], paB0.i[2]);
        xsw(pkf(p[2],p[3]),   pkf(p[6],p[7]),   paB0.i[1], paB0.i[3]);
        xsw(pkf(p[8],p[9]),   pkf(p[12],p[13]), paB1.i[0], paB1.i[2]);
        xsw(pkf(p[10],p[11]), pkf(p[14],p[15]), paB1.i[1], paB1.i[3]);
        paA0 = paB0; paA1 = paB1;

        // bar#1: all PV(t-1)/QK(t) LDS reads done block-wide -> vb slot free
        asm volatile("s_waitcnt lgkmcnt(0)\n\ts_barrier" ::: "memory");
        if (tt < 31) stageV(tt + 1, (tt + 1) & 1);
        // bar#2: drain K(t+1) (+older V), keep V(t+1)'s 4 DMAs in flight
        asm volatile("s_waitcnt vmcnt(4) lgkmcnt(0)\n\ts_barrier" ::: "memory");
    }

    // epilogue: PV(31) (V(31) must be fully landed in every wave)
    asm volatile("s_waitcnt vmcnt(0)" ::: "memory");
    __syncthreads();
    {
        const _Float16* vc = vb[half][1];
        #pragma unroll
        for (int nt = 0; nt < 8; ++nt) {
            const half8 vf0 = *(const half8*)(vc + nt*1024 + vo0);
            const half8 vf1 = *(const half8*)(vc + nt*1024 + vo1);
            o[nt] = __builtin_amdgcn_mfma_f32_32x32x16_f16(vf0, paA0.h8, o[nt], 0,0,0);
            o[nt] = __builtin_amdgcn_mfma_f32_32x32x16_f16(vf1, paA1.h8, o[nt], 0,0,0);
        }
    }
    __syncthreads();   // protect vb/kb before reuse as merge scratch

    // ---- in-block merge of kv halves (K/V LDS is dead scratch now) ----
    const float lT = lsum + __shfl_xor(lsum, 32, 64);
    float* ms = (strip < 2) ? ((float*)kb + strip * 8192)
                            : ((float*)vb + (strip - 2) * 8192);
    if (half == 1) {
        #pragma unroll
        for (int nt = 0; nt < 8; ++nt)
            #pragma unroll
            for (int r = 0; r < 16; ++r)
                ms[(nt*16 + r)*64 + lane] = o[nt][r];
        if (h == 0) { statM[strip*32 + jl] = M; statL[strip*32 + jl] = lT; }
    }
    __syncthreads();
    if (half == 0) {
        const float MB = statM[strip*32 + jl];
        const float lB = statL[strip*32 + jl];
        const float Mm = fmaxf(M, MB);
        const float aA = __builtin_amdgcn_exp2f((M  - Mm) * LOG2E);
        const float aB = __builtin_amdgcn_exp2f((MB - Mm) * LOG2E);
        const float osc = 1.0f / (16.0f * (aA*lT + aB*lB));
        #pragma unroll
        for (int nt = 0; nt < 8; ++nt) {
            #pragma unroll
            for (int r = 0; r < 16; ++r) {
                const int d = 32*nt + (r&3) + 8*(r>>2) + 4*h;
                ob[(size_t)d * S_ + i0 + jl] =
                    (aA*o[nt][r] + aB*ms[(nt*16 + r)*64 + lane]) * osc;
            }
        }
    }
}

extern "C" void kernel_launch(void* const* d_in, const int* in_sizes, int n_in,
                              void* d_out, int out_size, void* d_ws, size_t ws_size,
                              hipStream_t stream)
{
    const float* q    = (const float*)d_in[0];
    const float* k    = (const float*)d_in[1];   // [B][D][S]
    const float* v    = (const float*)d_in[2];   // [B][S][D]
    const int*   mask = (const int*)d_in[3];
    float*       out  = (float*)d_out;

    _Float16* kt  = (_Float16*)d_ws;              // [B][S][D] swizzled
    _Float16* vtp = kt + (size_t)B_ * S_ * D_;    // [B][D][S]

    tr_both<<<dim3(4096), dim3(256), 0, stream>>>(k, v, kt, vtp);
    attn_v11<<<dim3(B_ * (S_/128)), dim3(512), 0, stream>>>(q, kt, vtp, mask, out);
}